// Round 2
// baseline (102401.831 us; speedup 1.0000x reference)
//
#include <hip/hip_runtime.h>
#include <hip/hip_bf16.h>
#include <cstddef>

// ---------------------------------------------------------------------------
// UNet_config1 forward. fp32 compute, bf16 activation storage (arena 117 MB).
// Bilinear upsample is fused into the decoder concat-convs (never
// materialized). Layout NCHW, z-index = b*C + c.
// ---------------------------------------------------------------------------

typedef __hip_bfloat16 bf16;

__device__ __forceinline__ float ldb(const bf16* p) { return __bfloat162float(*p); }
__device__ __forceinline__ bf16 stb(float f) { return __float2bfloat16(f); }

// ---- 1. dynamic per-sample conv 8x8 pad 3 + PReLU[0] ----------------------
__global__ __launch_bounds__(256) void k_dynconv_prelu(
    const float* __restrict__ x,   // [8,1,256,256] fp32
    const float* __restrict__ w,   // [8,32,8,8] fp32
    const float* __restrict__ pa,
    bf16* __restrict__ out)        // [8,32,255,255]
{
    const int Hin = 256, Win = 256, Ho = 255, Wo = 255;
    int tx = threadIdx.x & 15, ty = threadIdx.x >> 4;
    int ox = blockIdx.x * 16 + tx;
    int oy = blockIdx.y * 16 + ty;
    int z  = blockIdx.z;            // b*32 + co
    if (ox >= Wo || oy >= Ho) return;
    int b = z >> 5;
    const float* wp = w + ((size_t)z << 6);
    const float* xp = x + (size_t)b * Hin * Win;
    float acc = 0.f;
#pragma unroll
    for (int ky = 0; ky < 8; ++ky) {
        int iy = oy + ky - 3;
        if ((unsigned)iy < (unsigned)Hin) {
            const float* row = xp + iy * Win;
#pragma unroll
            for (int kx = 0; kx < 8; ++kx) {
                int ix = ox + kx - 3;
                if ((unsigned)ix < (unsigned)Win)
                    acc += row[ix] * wp[ky * 8 + kx];
            }
        }
    }
    float a = pa[0];
    acc = (acc >= 0.f) ? acc : a * acc;
    out[((size_t)z * Ho + oy) * Wo + ox] = stb(acc);
}

// ---- generic single-source conv + optional PReLU --------------------------
template<int KH, int KW, int PAD>
__global__ __launch_bounds__(256) void k_conv_prelu(
    const bf16* __restrict__ in, int Cin, int H, int W, int Ho, int Wo,
    const float* __restrict__ wgt,   // [Cout][Cin][KH][KW] fp32
    const float* __restrict__ bias,
    const float* __restrict__ pa, int aidx,
    bf16* __restrict__ out, int Cout)
{
    int tx = threadIdx.x & 15, ty = threadIdx.x >> 4;
    int ox = blockIdx.x * 16 + tx;
    int oy = blockIdx.y * 16 + ty;
    int z  = blockIdx.z;            // b*Cout + co
    if (ox >= Wo || oy >= Ho) return;
    int co = z % Cout;
    int b  = z / Cout;
    const float* wp = wgt + (size_t)co * Cin * (KH * KW);
    float acc = bias[co];
    for (int c = 0; c < Cin; ++c) {
        const bf16* src = in + (size_t)(b * Cin + c) * H * W;
        const float* wc = wp + c * (KH * KW);
#pragma unroll
        for (int ky = 0; ky < KH; ++ky) {
            int iy = oy + ky - PAD;
            if ((unsigned)iy >= (unsigned)H) continue;
            const bf16* row = src + iy * W;
#pragma unroll
            for (int kx = 0; kx < KW; ++kx) {
                int ix = ox + kx - PAD;
                if ((unsigned)ix < (unsigned)W)
                    acc += ldb(row + ix) * wc[ky * KW + kx];
            }
        }
    }
    if (aidx >= 0) {
        float a = pa[aidx];
        acc = (acc >= 0.f) ? acc : a * acc;
    }
    out[((size_t)z * Ho + oy) * Wo + ox] = stb(acc);
}

// ---- decoder conv: 3x3 pad1 over concat( up2(low), skip ) + PReLU ---------
// low: [B,Cl,Hl,Wl], upsampled x2 bilinear align_corners on the fly.
// skip: [B,Cs,H,W] with H=2*Hl. Output [B,Cout,H,W].
__global__ __launch_bounds__(256) void k_convup_prelu(
    const bf16* __restrict__ low, int Cl, int Hl, int Wl,
    const bf16* __restrict__ skip, int Cs,
    const float* __restrict__ wgt,   // [Cout][Cl+Cs][3][3]
    const float* __restrict__ bias,
    const float* __restrict__ pa, int aidx,
    bf16* __restrict__ out, int Cout)
{
    const int H = 2 * Hl, W = 2 * Wl;
    int tx = threadIdx.x & 15, ty = threadIdx.x >> 4;
    int ox = blockIdx.x * 16 + tx;
    int oy = blockIdx.y * 16 + ty;
    int z  = blockIdx.z;
    if (ox >= W || oy >= H) return;
    int co = z % Cout;
    int b  = z / Cout;
    const float ry = (float)(Hl - 1) / (float)(H - 1);
    const float rx = (float)(Wl - 1) / (float)(W - 1);

    // per-tap bilinear coefficients (3 rows, 3 cols)
    int y0i[3], y1i[3], x0i[3], x1i[3];
    float fy[3], fx[3];
    bool vy[3], vx[3];
#pragma unroll
    for (int d = 0; d < 3; ++d) {
        int iy = oy - 1 + d;
        vy[d] = (unsigned)iy < (unsigned)H;
        int ix = ox - 1 + d;
        vx[d] = (unsigned)ix < (unsigned)W;
        float ys = vy[d] ? iy * ry : 0.f;
        float xs = vx[d] ? ix * rx : 0.f;
        y0i[d] = (int)floorf(ys); y1i[d] = min(y0i[d] + 1, Hl - 1);
        x0i[d] = (int)floorf(xs); x1i[d] = min(x0i[d] + 1, Wl - 1);
        fy[d] = ys - (float)y0i[d];
        fx[d] = xs - (float)x0i[d];
    }

    const int Cin = Cl + Cs;
    const float* wp = wgt + (size_t)co * Cin * 9;
    float acc = bias[co];

    for (int c = 0; c < Cl; ++c) {
        const bf16* p = low + (size_t)(b * Cl + c) * Hl * Wl;
        const float* wc = wp + c * 9;
#pragma unroll
        for (int dy = 0; dy < 3; ++dy) {
            if (!vy[dy]) continue;
            const bf16* r0 = p + y0i[dy] * Wl;
            const bf16* r1 = p + y1i[dy] * Wl;
            float gy = fy[dy];
#pragma unroll
            for (int dx = 0; dx < 3; ++dx) {
                if (!vx[dx]) continue;
                float v00 = ldb(r0 + x0i[dx]);
                float v01 = ldb(r0 + x1i[dx]);
                float v10 = ldb(r1 + x0i[dx]);
                float v11 = ldb(r1 + x1i[dx]);
                float gx = fx[dx];
                float c0 = v00 + (v10 - v00) * gy;
                float c1 = v01 + (v11 - v01) * gy;
                acc += (c0 + (c1 - c0) * gx) * wc[dy * 3 + dx];
            }
        }
    }
    for (int c = 0; c < Cs; ++c) {
        const bf16* p = skip + (size_t)(b * Cs + c) * H * W;
        const float* wc = wp + (Cl + c) * 9;
#pragma unroll
        for (int dy = 0; dy < 3; ++dy) {
            int iy = oy - 1 + dy;
            if ((unsigned)iy >= (unsigned)H) continue;
            const bf16* row = p + iy * W;
#pragma unroll
            for (int dx = 0; dx < 3; ++dx) {
                int ix = ox - 1 + dx;
                if ((unsigned)ix < (unsigned)W)
                    acc += ldb(row + ix) * wc[dy * 3 + dx];
            }
        }
    }
    float a = pa[aidx];
    acc = (acc >= 0.f) ? acc : a * acc;
    out[((size_t)z * H + oy) * W + ox] = stb(acc);
}

// ---- maxpool 2x2 stride 2 -------------------------------------------------
__global__ __launch_bounds__(256) void k_maxpool2(
    const bf16* __restrict__ in, bf16* __restrict__ out, int H, int W)
{
    int Ho = H >> 1, Wo = W >> 1;
    int tx = threadIdx.x & 15, ty = threadIdx.x >> 4;
    int ox = blockIdx.x * 16 + tx;
    int oy = blockIdx.y * 16 + ty;
    int z  = blockIdx.z;
    if (ox >= Wo || oy >= Ho) return;
    const bf16* p = in + ((size_t)z * H + oy * 2) * W + ox * 2;
    float m = fmaxf(fmaxf(ldb(p), ldb(p + 1)), fmaxf(ldb(p + W), ldb(p + W + 1)));
    out[((size_t)z * Ho + oy) * Wo + ox] = stb(m);
}

// ---- BatchNorm (training stats) -------------------------------------------
__global__ __launch_bounds__(256) void k_bn_stats(
    const bf16* __restrict__ x, int C, int HW, float* __restrict__ sums)
{
    int c = blockIdx.x, b = blockIdx.y;
    const bf16* p = x + (size_t)(b * C + c) * HW;
    float s = 0.f, q = 0.f;
    for (int i = threadIdx.x; i < HW; i += 256) {
        float v = ldb(p + i);
        s += v; q += v * v;
    }
    __shared__ float ls[256], lq[256];
    ls[threadIdx.x] = s; lq[threadIdx.x] = q;
    __syncthreads();
    for (int o = 128; o > 0; o >>= 1) {
        if (threadIdx.x < o) {
            ls[threadIdx.x] += ls[threadIdx.x + o];
            lq[threadIdx.x] += lq[threadIdx.x + o];
        }
        __syncthreads();
    }
    if (threadIdx.x == 0) {
        atomicAdd(&sums[c], ls[0]);
        atomicAdd(&sums[C + c], lq[0]);
    }
}

__global__ void k_bn_finalize(
    const float* __restrict__ sums, const float* __restrict__ g,
    const float* __restrict__ bta, int C, float invN, float* __restrict__ sc)
{
    int c = blockIdx.x * blockDim.x + threadIdx.x;
    if (c >= C) return;
    float mean = sums[c] * invN;
    float var  = sums[C + c] * invN - mean * mean;
    float r    = 1.0f / sqrtf(var + 1e-5f);
    float s    = g[c] * r;
    sc[c]      = s;
    sc[C + c]  = bta[c] - mean * s;
}

__global__ __launch_bounds__(256) void k_bn_apply(
    bf16* __restrict__ x, int C, int HW, const float* __restrict__ sc)
{
    int z = blockIdx.y;              // b*C + c
    int c = z % C;
    int i = blockIdx.x * 256 + threadIdx.x;
    if (i >= HW) return;
    bf16* p = x + (size_t)z * HW;
    p[i] = stb(ldb(p + i) * sc[c] + sc[C + c]);
}

// ---- final 1x1 conv, 32ch -> 1ch, fp32 out --------------------------------
__global__ __launch_bounds__(256) void k_final1x1(
    const bf16* __restrict__ in,     // [8,32,256,256]
    const float* __restrict__ w,     // [1,32,1,1]
    const float* __restrict__ bias,  // [1]
    float* __restrict__ out)         // [8,1,256,256]
{
    const int HW = 256 * 256;
    int i = blockIdx.x * 256 + threadIdx.x;
    int b = blockIdx.y;
    if (i >= HW) return;
    float acc = bias[0];
#pragma unroll
    for (int c = 0; c < 32; ++c)
        acc += ldb(in + (size_t)(b * 32 + c) * HW + i) * w[c];
    out[(size_t)b * HW + i] = acc;
}

extern "C" void kernel_launch(void* const* d_in, const int* in_sizes, int n_in,
                              void* d_out, int out_size, void* d_ws, size_t ws_size,
                              hipStream_t stream)
{
    const float* x      = (const float*)d_in[0];
    const float* w      = (const float*)d_in[1];
    const float* c1_w   = (const float*)d_in[2];
    const float* c1_b   = (const float*)d_in[3];
    const float* d2_w1  = (const float*)d_in[4];
    const float* d2_b1  = (const float*)d_in[5];
    const float* d2_w2  = (const float*)d_in[6];
    const float* d2_b2  = (const float*)d_in[7];
    const float* d3_w1  = (const float*)d_in[8];
    const float* d3_b1  = (const float*)d_in[9];
    const float* d3_w2  = (const float*)d_in[10];
    const float* d3_b2  = (const float*)d_in[11];
    const float* d4_w1  = (const float*)d_in[12];
    const float* d4_b1  = (const float*)d_in[13];
    const float* d4_w2  = (const float*)d_in[14];
    const float* d4_b2  = (const float*)d_in[15];
    const float* u3_w1  = (const float*)d_in[16];
    const float* u3_b1  = (const float*)d_in[17];
    const float* u3_w2  = (const float*)d_in[18];
    const float* u3_b2  = (const float*)d_in[19];
    const float* u2_w1  = (const float*)d_in[20];
    const float* u2_b1  = (const float*)d_in[21];
    const float* u2_w2  = (const float*)d_in[22];
    const float* u2_b2  = (const float*)d_in[23];
    const float* u1_w1  = (const float*)d_in[24];
    const float* u1_b1  = (const float*)d_in[25];
    const float* u1_w2  = (const float*)d_in[26];
    const float* u1_b2  = (const float*)d_in[27];
    const float* last_w = (const float*)d_in[28];
    const float* last_b = (const float*)d_in[29];
    const float* bn1_g  = (const float*)d_in[30];
    const float* bn1_b  = (const float*)d_in[31];
    const float* bn2_g  = (const float*)d_in[32];
    const float* bn2_b  = (const float*)d_in[33];
    const float* bn3_g  = (const float*)d_in[34];
    const float* bn3_b  = (const float*)d_in[35];
    const float* bn4_g  = (const float*)d_in[36];
    const float* bn4_b  = (const float*)d_in[37];
    const float* pa     = (const float*)d_in[38];
    float* out = (float*)d_out;

    // ---- bf16 arena, lifetime-overlapped. Total 117,448,704 bytes. ----
    bf16* A = (bf16*)d_ws;
    bf16* C1 = A;                        // 16,777,216 : c1 skip [8,32,256,256]
    bf16* C2 = A + 16777216;             // 16,777,216 : t0 / c2 / u2out / u1out
    bf16* C3 = A + 33554432;             //  8,388,608 : p1 / p2 / c3 / u3out
    bf16* Z  = A + 41943040;             // 16,777,216 : tmps (see sub-slots)
    bf16* t0    = C2;                    // 16,646,400 <= slot
    bf16* p1    = C3;                    //  4,194,304
    bf16* t1    = Z;                     // 16,777,216
    bf16* p2    = C3;                    //  4,194,304
    bf16* t2    = Z;                     //  8,388,608
    bf16* p3    = Z + 12582912;          //  2,097,152
    bf16* t3    = Z + 8388608;           //  4,194,304
    bf16* h4    = Z;                     //  4,194,304
    bf16* u3mid = Z + 4194304;           //  8,388,608
    bf16* u3out = C3;                    //  8,388,608
    bf16* u2mid = Z;                     // 16,777,216
    bf16* u2out = C2;                    // 16,777,216
    bf16* u1mid = Z;                     // 16,777,216
    bf16* u1out = C2;                    // 16,777,216
    float* SUMS = (float*)(A + 58720256);  // 1024 floats
    float* SC   = SUMS + 1024;             // 1024 floats
    size_t need = (size_t)58720256 * 2 + 2048 * 4;   // 117,448,704 B
    if (ws_size < need) return;

    dim3 blk(256);

    auto bn = [&](bf16* buf, int C, int HW, const float* g, const float* bb) {
        hipMemsetAsync(SUMS, 0, 2 * C * sizeof(float), stream);
        k_bn_stats<<<dim3(C, 8), blk, 0, stream>>>(buf, C, HW, SUMS);
        k_bn_finalize<<<dim3((C + 255) / 256), blk, 0, stream>>>(
            SUMS, g, bb, C, 1.0f / (8.0f * (float)HW), SC);
        k_bn_apply<<<dim3((HW + 255) / 256, 8 * C), blk, 0, stream>>>(buf, C, HW, SC);
    };

    // encoder
    k_dynconv_prelu<<<dim3(16, 16, 256), blk, 0, stream>>>(x, w, pa, t0);
    k_conv_prelu<4, 4, 2><<<dim3(16, 16, 256), blk, 0, stream>>>(
        t0, 32, 255, 255, 256, 256, c1_w, c1_b, pa, 1, C1, 32);
    bn(C1, 32, 65536, bn1_g, bn1_b);
    k_maxpool2<<<dim3(8, 8, 256), blk, 0, stream>>>(C1, p1, 256, 256);

    k_conv_prelu<3, 3, 1><<<dim3(8, 8, 1024), blk, 0, stream>>>(
        p1, 32, 128, 128, 128, 128, d2_w1, d2_b1, pa, 2, t1, 128);
    k_conv_prelu<3, 3, 1><<<dim3(8, 8, 1024), blk, 0, stream>>>(
        t1, 128, 128, 128, 128, 128, d2_w2, d2_b2, pa, 3, C2, 128);
    bn(C2, 128, 16384, bn2_g, bn2_b);
    k_maxpool2<<<dim3(4, 4, 1024), blk, 0, stream>>>(C2, p2, 128, 128);

    k_conv_prelu<3, 3, 1><<<dim3(4, 4, 2048), blk, 0, stream>>>(
        p2, 128, 64, 64, 64, 64, d3_w1, d3_b1, pa, 4, t2, 256);
    k_conv_prelu<3, 3, 1><<<dim3(4, 4, 2048), blk, 0, stream>>>(
        t2, 256, 64, 64, 64, 64, d3_w2, d3_b2, pa, 5, C3, 256);
    bn(C3, 256, 4096, bn3_g, bn3_b);
    k_maxpool2<<<dim3(2, 2, 2048), blk, 0, stream>>>(C3, p3, 64, 64);

    k_conv_prelu<3, 3, 1><<<dim3(2, 2, 4096), blk, 0, stream>>>(
        p3, 256, 32, 32, 32, 32, d4_w1, d4_b1, pa, 6, t3, 512);
    k_conv_prelu<3, 3, 1><<<dim3(2, 2, 4096), blk, 0, stream>>>(
        t3, 512, 32, 32, 32, 32, d4_w2, d4_b2, pa, 7, h4, 512);
    bn(h4, 512, 1024, bn4_g, bn4_b);

    // decoder (upsample fused into first conv of each double block)
    k_convup_prelu<<<dim3(4, 4, 2048), blk, 0, stream>>>(
        h4, 512, 32, 32, C3, 256, u3_w1, u3_b1, pa, 8, u3mid, 256);
    k_conv_prelu<3, 3, 1><<<dim3(4, 4, 2048), blk, 0, stream>>>(
        u3mid, 256, 64, 64, 64, 64, u3_w2, u3_b2, pa, 9, u3out, 256);

    k_convup_prelu<<<dim3(8, 8, 1024), blk, 0, stream>>>(
        u3out, 256, 64, 64, C2, 128, u2_w1, u2_b1, pa, 10, u2mid, 128);
    k_conv_prelu<3, 3, 1><<<dim3(8, 8, 1024), blk, 0, stream>>>(
        u2mid, 128, 128, 128, 128, 128, u2_w2, u2_b2, pa, 11, u2out, 128);

    k_convup_prelu<<<dim3(16, 16, 256), blk, 0, stream>>>(
        u2out, 128, 128, 128, C1, 32, u1_w1, u1_b1, pa, 12, u1mid, 32);
    k_conv_prelu<3, 3, 1><<<dim3(16, 16, 256), blk, 0, stream>>>(
        u1mid, 32, 256, 256, 256, 256, u1_w2, u1_b2, pa, 13, u1out, 32);

    k_final1x1<<<dim3(256, 8), blk, 0, stream>>>(u1out, last_w, last_b, out);
}

// Round 3
// 1679.106 us; speedup vs baseline: 60.9859x; 60.9859x over previous
//
#include <hip/hip_runtime.h>
#include <hip/hip_bf16.h>
#include <cstddef>

// ---------------------------------------------------------------------------
// UNet_config1 forward — MFMA implicit-GEMM, NHWC, fp16 storage / fp32 accum.
// Decoder upsample fused into conv LDS staging (no UP buffers).
// ---------------------------------------------------------------------------

typedef _Float16 h16;
typedef __attribute__((ext_vector_type(8))) _Float16 h16x8;
typedef __attribute__((ext_vector_type(4))) float f32x4;
union F8 { uint4 u; h16x8 h; };

__device__ __forceinline__ float h2f(unsigned short s) {
    union { h16 h; unsigned short s; } c; c.s = s; return (float)c.h;
}
__device__ __forceinline__ unsigned short f2h(float f) {
    union { h16 h; unsigned short s; } c; c.h = (h16)f; return c.s;
}
__device__ __forceinline__ unsigned pack2(float a, float b) {
    return (unsigned)f2h(a) | ((unsigned)f2h(b) << 16);
}
__device__ __forceinline__ void up8(const uint4& v, float* f) {
    f[0]=h2f(v.x&0xffff); f[1]=h2f(v.x>>16);
    f[2]=h2f(v.y&0xffff); f[3]=h2f(v.y>>16);
    f[4]=h2f(v.z&0xffff); f[5]=h2f(v.z>>16);
    f[6]=h2f(v.w&0xffff); f[7]=h2f(v.w>>16);
}

// ---- weight pack: fp32 [O][I][KH][KW] -> fp16 [O][T][I] -------------------
__global__ void k_pack(const float* __restrict__ w, h16* __restrict__ pw,
                       int I, int T)
{
    int i = blockIdx.x * 64 + threadIdx.x;
    if (i >= I) return;
    int t = blockIdx.y, o = blockIdx.z;
    pw[((size_t)o * T + t) * I + i] = (h16)w[((size_t)o * I + i) * T + t];
}

// ---- implicit-GEMM conv: 32 Cout x 256 px tile, 4 waves -------------------
// src1: channels [0,C1n). If UPS, src1 is low-res (H1,W1), bilinearly
// upsampled (align_corners) to (Hin,Win) during staging. src2: skip,
// channels [C1n,C1n+C2n), at (Hin,Win). Output (Ho,Wo) NHWC fp16.
template<int KH, int KW, int PAD, bool UPS>
__global__ __launch_bounds__(256, 2) void k_conv_mfma(
    const h16* __restrict__ src1, int C1n, int H1, int W1,
    const h16* __restrict__ src2, int C2n,
    int Hin, int Win, int Ho, int Wo,
    const h16* __restrict__ PW, const float* __restrict__ bias,
    const float* __restrict__ pa, int aidx,
    h16* __restrict__ out, int Cout)
{
    constexpr int WINH = 8 + KH - 1, WINW = 32 + KW - 1;
    constexpr int NPIX = WINH * WINW;
    constexpr int TAPS = KH * KW;
    __shared__ unsigned short lds[NPIX * 36];

    const int tid = threadIdx.x;
    const int lane = tid & 63, wv = tid >> 6;
    const int nCb = Cout >> 5;
    const int b  = blockIdx.z / nCb, cb = blockIdx.z % nCb;
    const int x0 = blockIdx.x * 32, y0 = blockIdx.y * 8;
    const int Cin = C1n + C2n;
    const int co_base = cb * 32;
    const int quad = lane >> 4, m16 = lane & 15;

    f32x4 acc[2][4];
#pragma unroll
    for (int i = 0; i < 2; ++i)
#pragma unroll
        for (int j = 0; j < 4; ++j) acc[i][j] = (f32x4){0.f, 0.f, 0.f, 0.f};

    const float ry = UPS ? (float)(H1 - 1) / (float)(Hin - 1) : 0.f;
    const float rx = UPS ? (float)(W1 - 1) / (float)(Win - 1) : 0.f;

    for (int c0 = 0; c0 < Cin; c0 += 32) {
        __syncthreads();
        // ---- stage 32-channel window into LDS (stride 36) ----
        const bool fromLow = (c0 < C1n);
        const h16* sp = fromLow ? src1 : src2;
        const int  sC = fromLow ? C1n : C2n;
        const int  cs = fromLow ? c0 : c0 - C1n;
        const int  sH = fromLow ? H1 : Hin;
        const int  sW = fromLow ? W1 : Win;

        if (UPS && fromLow) {
            for (int i = tid; i < NPIX * 4; i += 256) {
                int p = i >> 2, q = i & 3;
                int wy = p / WINW, wx = p - wy * WINW;
                int y = y0 - PAD + wy, x = x0 - PAD + wx;
                uint2 lo = {0u, 0u}, hi = {0u, 0u};
                if ((unsigned)y < (unsigned)Hin && (unsigned)x < (unsigned)Win) {
                    float ys = y * ry, xs = x * rx;
                    int yl0 = (int)ys, xl0 = (int)xs;
                    int yl1 = min(yl0 + 1, H1 - 1), xl1 = min(xl0 + 1, W1 - 1);
                    float fy = ys - (float)yl0, fx = xs - (float)xl0;
                    const h16* base = sp + (size_t)b * H1 * W1 * sC + cs + q * 8;
                    uint4 v00 = *(const uint4*)(base + (size_t)(yl0 * W1 + xl0) * sC);
                    uint4 v01 = *(const uint4*)(base + (size_t)(yl0 * W1 + xl1) * sC);
                    uint4 v10 = *(const uint4*)(base + (size_t)(yl1 * W1 + xl0) * sC);
                    uint4 v11 = *(const uint4*)(base + (size_t)(yl1 * W1 + xl1) * sC);
                    float a[8], bl[8], c[8], d[8], r[8];
                    up8(v00, a); up8(v01, bl); up8(v10, c); up8(v11, d);
#pragma unroll
                    for (int k = 0; k < 8; ++k) {
                        float r0 = a[k] + (c[k] - a[k]) * fy;
                        float r1 = bl[k] + (d[k] - bl[k]) * fy;
                        r[k] = r0 + (r1 - r0) * fx;
                    }
                    lo.x = pack2(r[0], r[1]); lo.y = pack2(r[2], r[3]);
                    hi.x = pack2(r[4], r[5]); hi.y = pack2(r[6], r[7]);
                }
                unsigned short* d = &lds[p * 36 + q * 8];
                ((uint2*)d)[0] = lo; ((uint2*)d)[1] = hi;
            }
        } else {
            for (int i = tid; i < NPIX * 4; i += 256) {
                int p = i >> 2, q = i & 3;
                int wy = p / WINW, wx = p - wy * WINW;
                int y = y0 - PAD + wy, x = x0 - PAD + wx;
                uint4 v = {0u, 0u, 0u, 0u};
                if ((unsigned)y < (unsigned)sH && (unsigned)x < (unsigned)sW)
                    v = *(const uint4*)(sp + ((size_t)((b * sH + y) * sW + x)) * sC + cs + q * 8);
                unsigned short* d = &lds[p * 36 + q * 8];
                ((uint2*)d)[0] = make_uint2(v.x, v.y);
                ((uint2*)d)[1] = make_uint2(v.z, v.w);
            }
        }
        __syncthreads();

        // ---- compute: TAPS x (2 A-frags, 4 B-frags, 8 MFMAs) ----
        const uint4* pwA0 = (const uint4*)(PW + ((size_t)(co_base + m16) * TAPS) * Cin + c0 + quad * 8);
        const uint4* pwA1 = (const uint4*)(PW + ((size_t)(co_base + 16 + m16) * TAPS) * Cin + c0 + quad * 8);
#pragma unroll
        for (int ky = 0; ky < KH; ++ky) {
#pragma unroll
            for (int kx = 0; kx < KW; ++kx) {
                const int tap = ky * KW + kx;
                F8 a0, a1;
                a0.u = pwA0[(tap * Cin) >> 3];
                a1.u = pwA1[(tap * Cin) >> 3];
#pragma unroll
                for (int nt = 0; nt < 4; ++nt) {
                    int rowl = (wv << 1) + (nt >> 1);
                    int col  = ((nt & 1) << 4) + m16;
                    int li = ((rowl + ky) * WINW + col + kx) * 36 + quad * 8;
                    F8 bf;
                    ((uint2*)&bf)[0] = *(const uint2*)&lds[li];
                    ((uint2*)&bf)[1] = *(const uint2*)&lds[li + 4];
                    acc[0][nt] = __builtin_amdgcn_mfma_f32_16x16x32_f16(a0.h, bf.h, acc[0][nt], 0, 0, 0);
                    acc[1][nt] = __builtin_amdgcn_mfma_f32_16x16x32_f16(a1.h, bf.h, acc[1][nt], 0, 0, 0);
                }
            }
        }
    }

    // ---- epilogue: bias + PReLU, NHWC store (4 consecutive co = 8B) ----
    const float alpha = pa[aidx];
#pragma unroll
    for (int mt = 0; mt < 2; ++mt) {
        int co = co_base + mt * 16 + quad * 4;
        float4 bi = *(const float4*)(bias + co);
#pragma unroll
        for (int nt = 0; nt < 4; ++nt) {
            int y = y0 + (wv << 1) + (nt >> 1);
            int x = x0 + ((nt & 1) << 4) + m16;
            float v0 = acc[mt][nt][0] + bi.x;
            float v1 = acc[mt][nt][1] + bi.y;
            float v2 = acc[mt][nt][2] + bi.z;
            float v3 = acc[mt][nt][3] + bi.w;
            v0 = v0 >= 0.f ? v0 : alpha * v0;
            v1 = v1 >= 0.f ? v1 : alpha * v1;
            v2 = v2 >= 0.f ? v2 : alpha * v2;
            v3 = v3 >= 0.f ? v3 : alpha * v3;
            uint2 r; r.x = pack2(v0, v1); r.y = pack2(v2, v3);
            *(uint2*)(out + ((size_t)((b * Ho + y) * Wo + x)) * Cout + co) = r;
        }
    }
}

// ---- dynamic per-sample conv 8x8 pad3 + PReLU[0], NHWC out ----------------
__global__ __launch_bounds__(256) void k_dynconv(
    const float* __restrict__ x,   // [8,256,256] fp32
    const float* __restrict__ w,   // [8,32,8,8] fp32
    const float* __restrict__ pa,
    h16* __restrict__ out)         // [8,255,255,32] NHWC
{
    __shared__ float wl[2048];     // [tap][co]
    int b = blockIdx.y;
    for (int j = threadIdx.x; j < 2048; j += 256) {
        int t = j >> 5, co = j & 31;
        wl[j] = w[((size_t)(b * 32 + co)) * 64 + t];
    }
    __syncthreads();
    int idx = blockIdx.x * 256 + threadIdx.x;
    if (idx >= 65025) return;
    int py = idx / 255, px = idx - py * 255;
    float acc[32];
#pragma unroll
    for (int c = 0; c < 32; ++c) acc[c] = 0.f;
    const float* xp = x + (size_t)b * 65536;
#pragma unroll
    for (int ky = 0; ky < 8; ++ky) {
        int iy = py + ky - 3;
        if ((unsigned)iy >= 256u) continue;
        const float* row = xp + iy * 256;
#pragma unroll
        for (int kx = 0; kx < 8; ++kx) {
            int ix = px + kx - 3;
            if ((unsigned)ix >= 256u) continue;
            float v = row[ix];
            const float4* wr = (const float4*)&wl[(ky * 8 + kx) * 32];
#pragma unroll
            for (int cg = 0; cg < 8; ++cg) {
                float4 wv = wr[cg];
                acc[cg*4+0] += v * wv.x; acc[cg*4+1] += v * wv.y;
                acc[cg*4+2] += v * wv.z; acc[cg*4+3] += v * wv.w;
            }
        }
    }
    float a = pa[0];
    h16* op = out + ((size_t)(b * 65025 + idx)) * 32;
#pragma unroll
    for (int cg = 0; cg < 4; ++cg) {
        float v[8];
#pragma unroll
        for (int k = 0; k < 8; ++k) {
            float t = acc[cg * 8 + k];
            v[k] = t >= 0.f ? t : a * t;
        }
        uint4 r;
        r.x = pack2(v[0], v[1]); r.y = pack2(v[2], v[3]);
        r.z = pack2(v[4], v[5]); r.w = pack2(v[6], v[7]);
        *(uint4*)(op + cg * 8) = r;
    }
}

// ---- maxpool 2x2, NHWC, vector 8ch ----------------------------------------
__global__ __launch_bounds__(256) void k_pool(
    const h16* __restrict__ in, h16* __restrict__ out,
    int Hin, int Win, int C, int lc8, int lwo, int count)
{
    int idx = blockIdx.x * 256 + threadIdx.x;
    if (idx >= count) return;
    int b = blockIdx.y;
    int c8 = idx & ((1 << lc8) - 1);
    int t  = idx >> lc8;
    int ox = t & ((1 << lwo) - 1);
    int oy = t >> lwo;
    const h16* p = in + ((size_t)((b * Hin + oy * 2) * Win + ox * 2)) * C + c8 * 8;
    uint4 v00 = *(const uint4*)p;
    uint4 v01 = *(const uint4*)(p + C);
    uint4 v10 = *(const uint4*)(p + (size_t)Win * C);
    uint4 v11 = *(const uint4*)(p + (size_t)Win * C + C);
    float a[8], bb[8], c[8], d[8];
    up8(v00, a); up8(v01, bb); up8(v10, c); up8(v11, d);
    uint4 r;
    float m[8];
#pragma unroll
    for (int k = 0; k < 8; ++k) m[k] = fmaxf(fmaxf(a[k], bb[k]), fmaxf(c[k], d[k]));
    r.x = pack2(m[0], m[1]); r.y = pack2(m[2], m[3]);
    r.z = pack2(m[4], m[5]); r.w = pack2(m[6], m[7]);
    int Wo = 1 << lwo;
    *(uint4*)(out + ((size_t)((b * (Hin >> 1) + oy) * Wo + ox)) * C + c8 * 8) = r;
}

// ---- BatchNorm (training stats), NHWC -------------------------------------
__global__ __launch_bounds__(256) void k_bnstats(
    const h16* __restrict__ x, int C, int N, float* __restrict__ sums)
{
    __shared__ float ls[1024];
    for (int j = threadIdx.x; j < 2 * C; j += 256) ls[j] = 0.f;
    __syncthreads();
    int start = blockIdx.x * 256 + threadIdx.x;
    int stride = gridDim.x * 256;      // multiple of C (grid=1024 -> 262144)
    int c = start & (C - 1);
    float s = 0.f, q = 0.f;
    for (int i = start; i < N; i += stride) {
        float v = h2f(((const unsigned short*)x)[i]);
        s += v; q += v * v;
    }
    atomicAdd(&ls[c], s);
    atomicAdd(&ls[C + c], q);
    __syncthreads();
    for (int j = threadIdx.x; j < 2 * C; j += 256) atomicAdd(&sums[j], ls[j]);
}

__global__ void k_bnfin(
    const float* __restrict__ sums, const float* __restrict__ g,
    const float* __restrict__ bta, int C, float invN, float* __restrict__ sc)
{
    int c = threadIdx.x;
    if (c >= C) return;
    float mean = sums[c] * invN;
    float var  = sums[C + c] * invN - mean * mean;
    float s    = g[c] / sqrtf(var + 1e-5f);
    sc[c]      = s;
    sc[C + c]  = bta[c] - mean * s;
}

__global__ __launch_bounds__(256) void k_bnapply(
    h16* __restrict__ x, int C, int N8, const float* __restrict__ sc)
{
    __shared__ float ls[1024];
    for (int j = threadIdx.x; j < 2 * C; j += 256) ls[j] = sc[j];
    __syncthreads();
    int idx = blockIdx.x * 256 + threadIdx.x;
    if (idx >= N8) return;
    int cb = (idx << 3) & (C - 1);
    h16* p = x + (size_t)idx * 8;
    uint4 v = *(const uint4*)p;
    float f[8];
    up8(v, f);
    uint4 r;
    float o[8];
#pragma unroll
    for (int k = 0; k < 8; ++k) o[k] = f[k] * ls[cb + k] + ls[C + cb + k];
    r.x = pack2(o[0], o[1]); r.y = pack2(o[2], o[3]);
    r.z = pack2(o[4], o[5]); r.w = pack2(o[6], o[7]);
    *(uint4*)p = r;
}

// ---- final 1x1 conv 32->1, fp32 out ---------------------------------------
__global__ __launch_bounds__(256) void k_final(
    const h16* __restrict__ in, const float* __restrict__ w,
    const float* __restrict__ bias, float* __restrict__ out)
{
    int idx = blockIdx.x * 256 + threadIdx.x;
    if (idx >= 524288) return;
    const h16* p = in + (size_t)idx * 32;
    float acc = bias[0];
#pragma unroll
    for (int cg = 0; cg < 4; ++cg) {
        uint4 v = *(const uint4*)(p + cg * 8);
        float f[8];
        up8(v, f);
#pragma unroll
        for (int k = 0; k < 8; ++k) acc += f[k] * w[cg * 8 + k];
    }
    out[idx] = acc;
}

extern "C" void kernel_launch(void* const* d_in, const int* in_sizes, int n_in,
                              void* d_out, int out_size, void* d_ws, size_t ws_size,
                              hipStream_t stream)
{
    const float* x      = (const float*)d_in[0];
    const float* w      = (const float*)d_in[1];
    const float* c1_w   = (const float*)d_in[2];
    const float* c1_b   = (const float*)d_in[3];
    const float* d2_w1  = (const float*)d_in[4];
    const float* d2_b1  = (const float*)d_in[5];
    const float* d2_w2  = (const float*)d_in[6];
    const float* d2_b2  = (const float*)d_in[7];
    const float* d3_w1  = (const float*)d_in[8];
    const float* d3_b1  = (const float*)d_in[9];
    const float* d3_w2  = (const float*)d_in[10];
    const float* d3_b2  = (const float*)d_in[11];
    const float* d4_w1  = (const float*)d_in[12];
    const float* d4_b1  = (const float*)d_in[13];
    const float* d4_w2  = (const float*)d_in[14];
    const float* d4_b2  = (const float*)d_in[15];
    const float* u3_w1  = (const float*)d_in[16];
    const float* u3_b1  = (const float*)d_in[17];
    const float* u3_w2  = (const float*)d_in[18];
    const float* u3_b2  = (const float*)d_in[19];
    const float* u2_w1  = (const float*)d_in[20];
    const float* u2_b1  = (const float*)d_in[21];
    const float* u2_w2  = (const float*)d_in[22];
    const float* u2_b2  = (const float*)d_in[23];
    const float* u1_w1  = (const float*)d_in[24];
    const float* u1_b1  = (const float*)d_in[25];
    const float* u1_w2  = (const float*)d_in[26];
    const float* u1_b2  = (const float*)d_in[27];
    const float* last_w = (const float*)d_in[28];
    const float* last_b = (const float*)d_in[29];
    const float* bn1_g  = (const float*)d_in[30];
    const float* bn1_b  = (const float*)d_in[31];
    const float* bn2_g  = (const float*)d_in[32];
    const float* bn2_b  = (const float*)d_in[33];
    const float* bn3_g  = (const float*)d_in[34];
    const float* bn3_b  = (const float*)d_in[35];
    const float* bn4_g  = (const float*)d_in[36];
    const float* bn4_b  = (const float*)d_in[37];
    const float* pa     = (const float*)d_in[38];
    float* out = (float*)d_out;

    // ---- fp16 arena (lifetime-overlapped), 166.3 MB total ----
    h16* A0 = (h16*)d_ws;
    h16* C1 = A0;                   // 16,777,216 : c1 skip  [8,256,256,32]
    h16* C2 = A0 + 16777216;        // 16,777,216 : c2 skip  [8,128,128,128]
    h16* C3 = A0 + 33554432;        //  8,388,608 : c3 skip  [8,64,64,256]
    h16* A  = A0 + 41943040;        // 16,777,216 : t0/t1/t2/t3/u3mid/u2mid/u1mid
    h16* B  = A0 + 58720256;        // 16,777,216 : p1/p2/p3/h4/u3out/u2out/u1out
    h16* PWb= A0 + 75497472;        //  7,628,800 : packed fp16 weights
    float* SUMS = (float*)(A0 + 83126272);   // 1024 f
    float* SC   = SUMS + 1024;               // 1024 f
    size_t need = (size_t)83126272 * 2 + 8192;
    if (ws_size < need) return;

    // packed-weight offsets
    h16* pw_c1   = PWb;             // 16384
    h16* pw_d2w1 = PWb + 16384;     // 36864
    h16* pw_d2w2 = PWb + 53248;     // 147456
    h16* pw_d3w1 = PWb + 200704;    // 294912
    h16* pw_d3w2 = PWb + 495616;    // 589824
    h16* pw_d4w1 = PWb + 1085440;   // 1179648
    h16* pw_d4w2 = PWb + 2265088;   // 2359296
    h16* pw_u3w1 = PWb + 4624384;   // 1769472
    h16* pw_u3w2 = PWb + 6393856;   // 589824
    h16* pw_u2w1 = PWb + 6983680;   // 442368
    h16* pw_u2w2 = PWb + 7426048;   // 147456
    h16* pw_u1w1 = PWb + 7573504;   // 46080
    h16* pw_u1w2 = PWb + 7619584;   // 9216

    dim3 blk(256);

    // weight packing
    auto pack = [&](const float* src, h16* dst, int I, int T, int O) {
        k_pack<<<dim3((I + 63) / 64, T, O), 64, 0, stream>>>(src, dst, I, T);
    };
    pack(c1_w,  pw_c1,   32, 16, 32);
    pack(d2_w1, pw_d2w1, 32,  9, 128);
    pack(d2_w2, pw_d2w2, 128, 9, 128);
    pack(d3_w1, pw_d3w1, 128, 9, 256);
    pack(d3_w2, pw_d3w2, 256, 9, 256);
    pack(d4_w1, pw_d4w1, 256, 9, 512);
    pack(d4_w2, pw_d4w2, 512, 9, 512);
    pack(u3_w1, pw_u3w1, 768, 9, 256);
    pack(u3_w2, pw_u3w2, 256, 9, 256);
    pack(u2_w1, pw_u2w1, 384, 9, 128);
    pack(u2_w2, pw_u2w2, 128, 9, 128);
    pack(u1_w1, pw_u1w1, 160, 9, 32);
    pack(u1_w2, pw_u1w2, 32,  9, 32);

    auto bn = [&](h16* buf, int C, int N, const float* g, const float* bb) {
        hipMemsetAsync(SUMS, 0, 2 * C * sizeof(float), stream);
        k_bnstats<<<dim3(1024), blk, 0, stream>>>(buf, C, N, SUMS);
        k_bnfin<<<dim3(1), dim3(512), 0, stream>>>(SUMS, g, bb, C, (float)C / (float)N, SC);
        k_bnapply<<<dim3(N / 8 / 256), blk, 0, stream>>>(buf, C, N / 8, SC);
    };

    // ---- encoder ----
    k_dynconv<<<dim3(255, 8), blk, 0, stream>>>(x, w, pa, A);   // t0 -> A
    k_conv_mfma<4,4,2,false><<<dim3(8, 32, 8), blk, 0, stream>>>(
        A, 32, 255, 255, nullptr, 0, 255, 255, 256, 256,
        pw_c1, c1_b, pa, 1, C1, 32);
    bn(C1, 32, 16777216, bn1_g, bn1_b);
    k_pool<<<dim3(256, 8), blk, 0, stream>>>(C1, B, 256, 256, 32, 2, 7, 65536);   // p1

    k_conv_mfma<3,3,1,false><<<dim3(4, 16, 32), blk, 0, stream>>>(
        B, 32, 128, 128, nullptr, 0, 128, 128, 128, 128,
        pw_d2w1, d2_b1, pa, 2, A, 128);                                            // t1
    k_conv_mfma<3,3,1,false><<<dim3(4, 16, 32), blk, 0, stream>>>(
        A, 128, 128, 128, nullptr, 0, 128, 128, 128, 128,
        pw_d2w2, d2_b2, pa, 3, C2, 128);
    bn(C2, 128, 16777216, bn2_g, bn2_b);
    k_pool<<<dim3(256, 8), blk, 0, stream>>>(C2, B, 128, 128, 128, 4, 6, 65536);  // p2

    k_conv_mfma<3,3,1,false><<<dim3(2, 8, 64), blk, 0, stream>>>(
        B, 128, 64, 64, nullptr, 0, 64, 64, 64, 64,
        pw_d3w1, d3_b1, pa, 4, A, 256);                                            // t2
    k_conv_mfma<3,3,1,false><<<dim3(2, 8, 64), blk, 0, stream>>>(
        A, 256, 64, 64, nullptr, 0, 64, 64, 64, 64,
        pw_d3w2, d3_b2, pa, 5, C3, 256);
    bn(C3, 256, 8388608, bn3_g, bn3_b);
    k_pool<<<dim3(128, 8), blk, 0, stream>>>(C3, B, 64, 64, 256, 5, 5, 32768);    // p3

    k_conv_mfma<3,3,1,false><<<dim3(1, 4, 128), blk, 0, stream>>>(
        B, 256, 32, 32, nullptr, 0, 32, 32, 32, 32,
        pw_d4w1, d4_b1, pa, 6, A, 512);                                            // t3
    k_conv_mfma<3,3,1,false><<<dim3(1, 4, 128), blk, 0, stream>>>(
        A, 512, 32, 32, nullptr, 0, 32, 32, 32, 32,
        pw_d4w2, d4_b2, pa, 7, B, 512);                                            // h4
    bn(B, 512, 4194304, bn4_g, bn4_b);

    // ---- decoder (bilinear up2 fused into staging) ----
    k_conv_mfma<3,3,1,true><<<dim3(2, 8, 64), blk, 0, stream>>>(
        B, 512, 32, 32, C3, 256, 64, 64, 64, 64,
        pw_u3w1, u3_b1, pa, 8, A, 256);                                            // u3mid
    k_conv_mfma<3,3,1,false><<<dim3(2, 8, 64), blk, 0, stream>>>(
        A, 256, 64, 64, nullptr, 0, 64, 64, 64, 64,
        pw_u3w2, u3_b2, pa, 9, B, 256);                                            // u3out

    k_conv_mfma<3,3,1,true><<<dim3(4, 16, 32), blk, 0, stream>>>(
        B, 256, 64, 64, C2, 128, 128, 128, 128, 128,
        pw_u2w1, u2_b1, pa, 10, A, 128);                                           // u2mid
    k_conv_mfma<3,3,1,false><<<dim3(4, 16, 32), blk, 0, stream>>>(
        A, 128, 128, 128, nullptr, 0, 128, 128, 128, 128,
        pw_u2w2, u2_b2, pa, 11, B, 128);                                           // u2out

    k_conv_mfma<3,3,1,true><<<dim3(8, 32, 8), blk, 0, stream>>>(
        B, 128, 128, 128, C1, 32, 256, 256, 256, 256,
        pw_u1w1, u1_b1, pa, 12, A, 32);                                            // u1mid
    k_conv_mfma<3,3,1,false><<<dim3(8, 32, 8), blk, 0, stream>>>(
        A, 32, 256, 256, nullptr, 0, 256, 256, 256, 256,
        pw_u1w2, u1_b2, pa, 13, B, 32);                                            // u1out

    k_final<<<dim3(2048), blk, 0, stream>>>(B, last_w, last_b, out);
}